// Round 3
// baseline (648.680 us; speedup 1.0000x reference)
//
#include <hip/hip_runtime.h>

// x[32,8,512,512] fp32 -> out[32,512,32] fp32. Element (r,w) belongs to one
// shell per corner: TL bin max(r,w), TR max(r,511-w), BL max(511-r,w),
// BR max(511-r,511-w). One streaming pass (268 MB) => roofline ~43 us.
//
// Identities (p(j)=prefix of row r, T=row total, colA[r]=col-r cumsum thru
// row r, colB[r]=same at col 511-r, total[c]=col totals):
//   TL[r]     = p(r-1)   + colA[r]
//   TR[r]     = T - p(511-r) + colB[r]
//   BL[511-r] = p(511-r) + total[511-r] - colB[r]
//   BR[511-r] = T - p(r-1) + total[r]   - colA[r]
//
// R2 lesson: dur_us is dominated by ~310 us of harness fills/restores (1 GiB
// d_ws poison = 160 us alone); kernels are ~55 us combined. This round: fuse
// the cross-strip fixup into the main kernel via a per-plane device-scope
// completion counter (last block of each plane does the fixup while wsA/wsBT
// are still L2/L3-warm), and unroll the row loop by 8 so the diagonal
// column-extract ladders become compile-time register picks.

#define PLANES 256   // B*C
#define WW     512
#define HH     512
#define JBLK   16    // row-strips per plane (one wave each)
#define RPB    32    // rows per strip
#define WPB    4     // waves per block -> 4 blocks per plane
#define BPP    (JBLK / WPB)
#define PF     4     // prefetch depth in rows

// Full 64-lane sum via DPP (VALU pipe). Result valid in lane 63.
__device__ __forceinline__ float wave_sum64(float v) {
  v += __int_as_float(__builtin_amdgcn_update_dpp(0, __float_as_int(v), 0x111, 0xf, 0xf, true)); // row_shr:1
  v += __int_as_float(__builtin_amdgcn_update_dpp(0, __float_as_int(v), 0x112, 0xf, 0xf, true)); // row_shr:2
  v += __int_as_float(__builtin_amdgcn_update_dpp(0, __float_as_int(v), 0x114, 0xf, 0xf, true)); // row_shr:4
  v += __int_as_float(__builtin_amdgcn_update_dpp(0, __float_as_int(v), 0x118, 0xf, 0xf, true)); // row_shr:8
  v += __int_as_float(__builtin_amdgcn_update_dpp(0, __float_as_int(v), 0x142, 0xf, 0xf, true)); // row_bcast:15
  v += __int_as_float(__builtin_amdgcn_update_dpp(0, __float_as_int(v), 0x143, 0xf, 0xf, true)); // row_bcast:31
  return v;
}

__global__ __launch_bounds__(256, 4)
void corner_fused(const float* __restrict__ x, float* __restrict__ wsA,
                  float* __restrict__ wsBT, unsigned* __restrict__ counters,
                  float* __restrict__ out) {
  const int t     = threadIdx.x;
  const int lane  = t & 63;
  const int wv    = t >> 6;
  const int plane = blockIdx.y;
  const int jb    = blockIdx.x * WPB + wv;   // this wave's strip
  const int r0    = jb * RPB;                // multiple of 32 -> (r0+rr)&7 == rr&7
  const int c0    = lane << 3;               // first of 8 owned columns

  const float4* base = (const float4*)(x + (size_t)plane * HH * WW + (size_t)r0 * WW);
  const int li = lane * 2;                   // float4 index of first owned half

  float4 b0[PF], b1[PF];                     // register prefetch pipeline
#pragma unroll
  for (int i = 0; i < PF; ++i) {
    b0[i] = base[i * 128 + li];
    b1[i] = base[i * 128 + li + 1];
  }

  float cs[8] = {0.f, 0.f, 0.f, 0.f, 0.f, 0.f, 0.f, 0.f};  // private column sums

  for (int rr8 = 0; rr8 < RPB; rr8 += 8) {
#pragma unroll
    for (int u = 0; u < 8; ++u) {            // u == r&7 (compile-time per slot)
      const int rr = rr8 + u;
      const int r  = r0 + rr;
      const int q  = 511 - r;

      const float4 va = b0[rr & (PF - 1)];
      const float4 vb = b1[rr & (PF - 1)];
      if (rr + PF < RPB) {                   // wave-uniform branch
        b0[rr & (PF - 1)] = base[(rr + PF) * 128 + li];
        b1[rr & (PF - 1)] = base[(rr + PF) * 128 + li + 1];
      }

      cs[0] += va.x; cs[1] += va.y; cs[2] += va.z; cs[3] += va.w;
      cs[4] += vb.x; cs[5] += vb.y; cs[6] += vb.z; cs[7] += vb.w;

      // in-lane prefix of the 8 owned elements
      const float p0 = va.x, p1 = p0 + va.y, p2 = p1 + va.z, p3 = p2 + va.w;
      const float p4 = p3 + vb.x, p5 = p4 + vb.y, p6 = p5 + vb.z, p7 = p6 + vb.w;

      // masked sums: cols <= r-1 and cols <= 511-r
      const int lt1 = (r - 1) - c0;
      const int lt2 = q - c0;
      float m1 = 0.f;
      m1 = (lt1 >= 0) ? p0 : m1; m1 = (lt1 >= 1) ? p1 : m1;
      m1 = (lt1 >= 2) ? p2 : m1; m1 = (lt1 >= 3) ? p3 : m1;
      m1 = (lt1 >= 4) ? p4 : m1; m1 = (lt1 >= 5) ? p5 : m1;
      m1 = (lt1 >= 6) ? p6 : m1; m1 = (lt1 >= 7) ? p7 : m1;
      float m2 = 0.f;
      m2 = (lt2 >= 0) ? p0 : m2; m2 = (lt2 >= 1) ? p1 : m2;
      m2 = (lt2 >= 2) ? p2 : m2; m2 = (lt2 >= 3) ? p3 : m2;
      m2 = (lt2 >= 4) ? p4 : m2; m2 = (lt2 >= 5) ? p5 : m2;
      m2 = (lt2 >= 6) ? p6 : m2; m2 = (lt2 >= 7) ? p7 : m2;

      float T = p7;
      T  = wave_sum64(T);                    // 3 independent DPP chains
      m1 = wave_sum64(m1);
      m2 = wave_sum64(m2);

      // diagonal column extracts: r&7 == u, q&7 == 7-u (compile-time picks)
      const float a = __shfl(cs[u],     r >> 3, 64);  // colsum incl r at col r
      const float b = __shfl(cs[7 - u], q >> 3, 64);  // colsum incl r at col q

      if (lane == 63) {                      // T,m1,m2 valid in lane 63
        float4 A;
        A.x = m1 + a;                        // TL[r]  (+ prev[r] in fixup)
        A.y = T - m2 + b;                    // TR[r]  (+ prev[q])
        A.z = m2 - b;                        // BL[q]  (+ tot[q] - prev[q])
        A.w = T - m1 - a;                    // BR[q]  (+ tot[r] - prev[r])
        ((float4*)wsA)[(size_t)plane * 512 + r] = A;
      }
    }
  }

  // per-strip column totals: lane's 8 contiguous cols -> two float4 stores
  {
    float4* bt = (float4*)(wsBT + ((size_t)plane * JBLK + jb) * WW + c0);
    bt[0] = make_float4(cs[0], cs[1], cs[2], cs[3]);
    bt[1] = make_float4(cs[4], cs[5], cs[6], cs[7]);
  }

  // ---- completion: last block of this plane performs the fixup ----
  __shared__ int sdone;
  __syncthreads();                 // drains each wave's stores to L2 (vmcnt(0))
  __threadfence();                 // device-scope release (L2 writeback)
  if (t == 0) {
    const unsigned old = atomicAdd(&counters[plane], 1u);
    sdone = (old == BPP - 1);
  }
  __syncthreads();
  if (!sdone) return;
  __threadfence();                 // device-scope acquire (invalidate stale)

  const float*  btp = wsBT + (size_t)plane * JBLK * WW;
  const float4* Ap  = (const float4*)wsA + (size_t)plane * 512;
  const int bb = plane >> 3, cc = plane & 7;
  float* ob = out + (size_t)bb * 512 * 32;

#pragma unroll
  for (int h = 0; h < 2; ++h) {
    const int r = t + h * 256;
    const int q = 511 - r;
    const float4 A = Ap[r];

    const int jbr = r >> 5;        // strip containing row r (RPB = 32)
    float prev_r = 0.f, tot_r = 0.f, prev_q = 0.f, tot_q = 0.f;
#pragma unroll
    for (int jj = 0; jj < JBLK; ++jj) {
      const float br_ = btp[jj * WW + r];
      const float bq_ = btp[jj * WW + q];
      tot_r += br_; tot_q += bq_;
      if (jj < jbr) { prev_r += br_; prev_q += bq_; }
    }

    const float TL = A.x + prev_r;
    const float TR = A.y + prev_q;
    const float BL = A.z + (tot_q - prev_q);
    const float BR = A.w + (tot_r - prev_r);

    const float invr = 1.0f / (float)(2 * r + 1);   // counts[i] = 2i+1
    const float invq = 1.0f / (float)(2 * q + 1);

    ob[r * 32 + cc]      = TL * invr;
    ob[r * 32 + 8 + cc]  = TR * invr;
    ob[q * 32 + 16 + cc] = BL * invq;
    ob[q * 32 + 24 + cc] = BR * invq;
  }
}

extern "C" void kernel_launch(void* const* d_in, const int* in_sizes, int n_in,
                              void* d_out, int out_size, void* d_ws, size_t ws_size,
                              hipStream_t stream) {
  const float* x = (const float*)d_in[0];
  float* out = (float*)d_out;

  // ws layout: wsA 2 MB | wsBT 8 MB | counters 1 KB
  float*    wsA      = (float*)d_ws;
  float*    wsBT     = wsA + (size_t)PLANES * 512 * 4;
  unsigned* counters = (unsigned*)(wsBT + (size_t)PLANES * JBLK * WW);

  hipMemsetAsync(counters, 0, PLANES * sizeof(unsigned), stream);

  dim3 g1(BPP, PLANES);                      // 4 x 256 blocks, 4 waves each
  corner_fused<<<g1, 256, 0, stream>>>(x, wsA, wsBT, counters, out);
}

// Round 4
// 366.950 us; speedup vs baseline: 1.7678x; 1.7678x over previous
//
#include <hip/hip_runtime.h>

// x[32,8,512,512] fp32 -> out[32,512,32] fp32. Element (r,w) belongs to one
// shell per corner: TL bin max(r,w), TR max(r,511-w), BL max(511-r,w),
// BR max(511-r,511-w). One streaming pass (268 MB) => roofline ~43 us.
//
// Identities (p(j)=prefix of row r, T=row total, colA[r]=col-r cumsum thru
// row r, colB[r]=same at col 511-r, total[c]=col totals):
//   TL[r]     = p(r-1)   + colA[r]
//   TR[r]     = T - p(511-r) + colB[r]
//   BL[511-r] = p(511-r) + total[511-r] - colB[r]
//   BR[511-r] = T - p(r-1) + total[r]   - colA[r]
//
// R1 lesson: per-row __syncthreads -> vmcnt(0) drain per row -> latency bound.
// R3 lesson: single-kernel fusion via completion counter + __threadfence()
//   regressed 8x: agent-scope fences on multi-XCD CDNA4 emit per-XCD L2
//   writeback/invalidate (buffer_wbl2/buffer_inv); 1024 blocks x L2 flush
//   serialized the whole kernel (420 us @ 5% HBM). The kernel-launch boundary
//   gives cross-XCD coherence for free -> keep the two-kernel structure.
//
// Structure: one wave owns a full row (64 lanes x 8 cols, two float4 loads).
// All reductions intra-wave (DPP + shfl), zero barriers/LDS in the main loop;
// 4-deep register prefetch stays in flight. Row loop unrolled by 8 so the
// diagonal column extracts cs[r&7] are compile-time register picks.

#define PLANES 256   // B*C
#define WW     512
#define HH     512
#define JBLK   16    // row-strips per plane (one wave each)
#define RPB    32    // rows per strip
#define WPB    4     // waves per block
#define PF     4     // prefetch depth in rows

// Full 64-lane sum via DPP (VALU pipe). Result valid in lane 63.
__device__ __forceinline__ float wave_sum64(float v) {
  v += __int_as_float(__builtin_amdgcn_update_dpp(0, __float_as_int(v), 0x111, 0xf, 0xf, true)); // row_shr:1
  v += __int_as_float(__builtin_amdgcn_update_dpp(0, __float_as_int(v), 0x112, 0xf, 0xf, true)); // row_shr:2
  v += __int_as_float(__builtin_amdgcn_update_dpp(0, __float_as_int(v), 0x114, 0xf, 0xf, true)); // row_shr:4
  v += __int_as_float(__builtin_amdgcn_update_dpp(0, __float_as_int(v), 0x118, 0xf, 0xf, true)); // row_shr:8
  v += __int_as_float(__builtin_amdgcn_update_dpp(0, __float_as_int(v), 0x142, 0xf, 0xf, true)); // row_bcast:15
  v += __int_as_float(__builtin_amdgcn_update_dpp(0, __float_as_int(v), 0x143, 0xf, 0xf, true)); // row_bcast:31
  return v;
}

__global__ __launch_bounds__(256, 4)
void corner_pass1(const float* __restrict__ x, float* __restrict__ wsA,
                  float* __restrict__ wsBT) {
  const int t     = threadIdx.x;
  const int lane  = t & 63;
  const int wv    = t >> 6;
  const int plane = blockIdx.y;
  const int jb    = blockIdx.x * WPB + wv;   // this wave's strip
  const int r0    = jb * RPB;                // multiple of 32 -> (r0+rr)&7 == rr&7
  const int c0    = lane << 3;               // first of 8 owned columns

  const float4* base = (const float4*)(x + (size_t)plane * HH * WW + (size_t)r0 * WW);
  const int li = lane * 2;                   // float4 index of first owned half

  float4 b0[PF], b1[PF];                     // register prefetch pipeline
#pragma unroll
  for (int i = 0; i < PF; ++i) {
    b0[i] = base[i * 128 + li];
    b1[i] = base[i * 128 + li + 1];
  }

  float cs[8] = {0.f, 0.f, 0.f, 0.f, 0.f, 0.f, 0.f, 0.f};  // private column sums

  for (int rr8 = 0; rr8 < RPB; rr8 += 8) {
#pragma unroll
    for (int u = 0; u < 8; ++u) {            // u == r&7 (compile-time per slot)
      const int rr = rr8 + u;
      const int r  = r0 + rr;
      const int q  = 511 - r;

      const float4 va = b0[rr & (PF - 1)];
      const float4 vb = b1[rr & (PF - 1)];
      if (rr + PF < RPB) {                   // wave-uniform branch
        b0[rr & (PF - 1)] = base[(rr + PF) * 128 + li];
        b1[rr & (PF - 1)] = base[(rr + PF) * 128 + li + 1];
      }

      cs[0] += va.x; cs[1] += va.y; cs[2] += va.z; cs[3] += va.w;
      cs[4] += vb.x; cs[5] += vb.y; cs[6] += vb.z; cs[7] += vb.w;

      // in-lane prefix of the 8 owned elements
      const float p0 = va.x, p1 = p0 + va.y, p2 = p1 + va.z, p3 = p2 + va.w;
      const float p4 = p3 + vb.x, p5 = p4 + vb.y, p6 = p5 + vb.z, p7 = p6 + vb.w;

      // masked sums: cols <= r-1 and cols <= 511-r
      const int lt1 = (r - 1) - c0;
      const int lt2 = q - c0;
      float m1 = 0.f;
      m1 = (lt1 >= 0) ? p0 : m1; m1 = (lt1 >= 1) ? p1 : m1;
      m1 = (lt1 >= 2) ? p2 : m1; m1 = (lt1 >= 3) ? p3 : m1;
      m1 = (lt1 >= 4) ? p4 : m1; m1 = (lt1 >= 5) ? p5 : m1;
      m1 = (lt1 >= 6) ? p6 : m1; m1 = (lt1 >= 7) ? p7 : m1;
      float m2 = 0.f;
      m2 = (lt2 >= 0) ? p0 : m2; m2 = (lt2 >= 1) ? p1 : m2;
      m2 = (lt2 >= 2) ? p2 : m2; m2 = (lt2 >= 3) ? p3 : m2;
      m2 = (lt2 >= 4) ? p4 : m2; m2 = (lt2 >= 5) ? p5 : m2;
      m2 = (lt2 >= 6) ? p6 : m2; m2 = (lt2 >= 7) ? p7 : m2;

      float T = p7;
      T  = wave_sum64(T);                    // 3 independent DPP chains
      m1 = wave_sum64(m1);
      m2 = wave_sum64(m2);

      // diagonal column extracts: r&7 == u, q&7 == 7-u (compile-time picks)
      const float a = __shfl(cs[u],     r >> 3, 64);  // colsum incl r at col r
      const float b = __shfl(cs[7 - u], q >> 3, 64);  // colsum incl r at col q

      if (lane == 63) {                      // T,m1,m2 valid in lane 63
        float4 A;
        A.x = m1 + a;                        // TL[r]  (+ prev[r] in pass 2)
        A.y = T - m2 + b;                    // TR[r]  (+ prev[q])
        A.z = m2 - b;                        // BL[q]  (+ tot[q] - prev[q])
        A.w = T - m1 - a;                    // BR[q]  (+ tot[r] - prev[r])
        ((float4*)wsA)[(size_t)plane * 512 + r] = A;
      }
    }
  }

  // per-strip column totals: lane's 8 contiguous cols -> two float4 stores
  float4* bt = (float4*)(wsBT + ((size_t)plane * JBLK + jb) * WW + c0);
  bt[0] = make_float4(cs[0], cs[1], cs[2], cs[3]);
  bt[1] = make_float4(cs[4], cs[5], cs[6], cs[7]);
}

// Pass 2: cross-strip column-prefix fixup + count division + scatter to out.
// Kernel-launch boundary supplies cross-XCD coherence (no fences needed).
__global__ __launch_bounds__(256)
void corner_pass2(const float* __restrict__ wsA, const float* __restrict__ wsBT,
                  float* __restrict__ out) {
  const int idx   = blockIdx.x * 256 + threadIdx.x;  // 0..131071
  const int plane = idx >> 9;
  const int r     = idx & 511;
  const int q     = 511 - r;

  const float4 A  = ((const float4*)wsA)[idx];
  const float* bt = wsBT + (size_t)plane * JBLK * 512;

  const int jb = r >> 5;  // strip containing row r (RPB = 32)
  float prev_r = 0.f, tot_r = 0.f, prev_q = 0.f, tot_q = 0.f;
#pragma unroll
  for (int jj = 0; jj < JBLK; ++jj) {
    const float br_ = bt[jj * 512 + r];
    const float bq_ = bt[jj * 512 + q];
    tot_r += br_; tot_q += bq_;
    if (jj < jb) { prev_r += br_; prev_q += bq_; }
  }

  const float TL = A.x + prev_r;
  const float TR = A.y + prev_q;
  const float BL = A.z + (tot_q - prev_q);
  const float BR = A.w + (tot_r - prev_r);

  const float invr = 1.0f / (float)(2 * r + 1);   // counts[i] = 2i+1
  const float invq = 1.0f / (float)(2 * q + 1);

  const int b = plane >> 3, c = plane & 7;
  float* ob = out + (size_t)b * 512 * 32;
  ob[r * 32 + c]      = TL * invr;
  ob[r * 32 + 8 + c]  = TR * invr;
  ob[q * 32 + 16 + c] = BL * invq;
  ob[q * 32 + 24 + c] = BR * invq;
}

extern "C" void kernel_launch(void* const* d_in, const int* in_sizes, int n_in,
                              void* d_out, int out_size, void* d_ws, size_t ws_size,
                              hipStream_t stream) {
  const float* x = (const float*)d_in[0];
  float* out = (float*)d_out;

  // ws layout: wsA 2 MB (per-row float4) | wsBT 8 MB (per-strip column totals)
  float* wsA  = (float*)d_ws;
  float* wsBT = wsA + (size_t)PLANES * 512 * 4;

  dim3 g1(JBLK / WPB, PLANES);               // 4 x 256 blocks, 4 waves each
  corner_pass1<<<g1, 256, 0, stream>>>(x, wsA, wsBT);
  corner_pass2<<<512, 256, 0, stream>>>(wsA, wsBT, out);
}